// Round 1
// baseline (241.591 us; speedup 1.0000x reference)
//
#include <hip/hip_runtime.h>
#include <math.h>

// DTW 2048x2048, squared-diff cost, out = sqrt(DTW[2047][2047]).
//
// Skew-2 wave pipeline, NW=4 waves (256 thr) on one CU, R=8 rows/lane,
// split into TWO independent 4-row half-chains per lane:
//   chainL: rows 8L..8L+3 at column jL = t - 2*lane
//   chainH: rows 8L+4..8L+7 at column jH = jL - 1   (lags one column)
// chainH's inputs at step t (own v4..v7 from t-1, nv3 from t-1 (above) and
// t-2 (diag), y[jH] = previous step's yconv) are all ready at step start,
// so the two 4-cell chains overlap: per-step dependent chain = 4 cells
// (min3+fma each, v_min3_f32 forced via inline asm) instead of 8.
// Lane-skew must be 2 (row 7 completes one step after row 0's column),
// hence DSKEW=192, PAD=128, GTOT=2752 (+10% steps for ~2x less latency).
//
// Conveyors (zero per-step LDS reads, same scheme as the skew-1 version):
//   y: lane l needs y[t-2l] -> conveyor advances one lane every TWO steps:
//      yc(t) = dpp_shr1(yd, inj=y[t]); yd(t) = yc(t-1). chainH uses the
//      pre-update yc (= y[t-1-2l] = y[jH]).
//   u: lane l row0 needs DTW[R0-1][jL] = lane l-1's row7 at col t-2l,
//      which lane l-1 (chainH, lagging) finished at step t-1 -> plain
//      dpp_shr1(v7, inj=ring[t]) exactly as before. uprev = u(t-1) = diag.
//
// Guard-free: INFV=1e30 absorbs adds (1e30 + d^2 == 1e30 fp32), junk stays
// tagged to its column (conveyors preserve column identity), and columns
// >= 2048 (clamped-y fakes) can never influence column 2047. OOB ring
// writes land in pads. Ring producer/consumer: consumer block-top read
// touches cols <= tau0+63; producer lane63 writes col c at step c+127;
// DSKEW=192 guarantees producer completed step tau0+191 >= tau0+190.
//
// Output: row 2047 = w3/lane63/chainH-bottom, col 2047 at step
// 2047 + 2*63 + 1 = 2174 = tau0 2112 (=TAUMAX), s=62.

#define NLEN  2048
#define NW    4
#define CSTEP 64
#define DSKEW 192
#define PAD   128
#define TAUMAX (NLEN + CSTEP)                    // 2112: full drain of skew-2 pipe
#define RROW  (PAD + NLEN + 2 * CSTEP)           // 2304: cols -128..2175
#define GTOT  (TAUMAX + (NW - 1) * DSKEW + CSTEP) // 2752
#define INFV  1e30f

__device__ __forceinline__ float dpp_shr1(float v, float inj) {
    int r = __builtin_amdgcn_update_dpp(
        __builtin_bit_cast(int, inj), __builtin_bit_cast(int, v),
        0x138 /*wave_shr:1*/, 0xF, 0xF, false /*lane0 keeps old=inj*/);
    return __builtin_bit_cast(float, r);
}
__device__ __forceinline__ float rdlane(float v, int l) {
    return __builtin_bit_cast(float,
        __builtin_amdgcn_readlane(__builtin_bit_cast(int, v), l));
}
// Force single-instruction 3-input min: the per-cell chain must be
// exactly (v_min3_f32 -> v_fmac); an unfused fminf(fminf()) pair adds
// ~50% to the carried dependency chain.
__device__ __forceinline__ float min3f(float a, float b, float c) {
    float r;
    asm("v_min3_f32 %0, %1, %2, %3" : "=v"(r) : "v"(a), "v"(b), "v"(c));
    return r;
}

__global__ __launch_bounds__(256, 1) void dtw_kernel(const float* __restrict__ X,
                                                     const float* __restrict__ Y,
                                                     float* __restrict__ out) {
    __shared__ __align__(16) float yS[NLEN];
    __shared__ float ring[(NW + 1) * RROW];

    const int tid  = threadIdx.x;
    const int w    = tid >> 6;
    const int lane = tid & 63;

    {
        const float4* Y4 = (const float4*)Y;
        float4* y4 = (float4*)yS;
        y4[tid]       = Y4[tid];
        y4[tid + 256] = Y4[tid + 256];
    }
    // Entire ring INFV: virtual row -1, pads, and unwritten tails.
    for (int k = tid; k < (NW + 1) * RROW; k += 256) ring[k] = INFV;
    __syncthreads();

    float x0, x1, x2, x3, x4, x5, x6, x7;
    {
        const float4 xa = *(const float4*)&X[tid * 8];
        const float4 xb = *(const float4*)&X[tid * 8 + 4];
        x0 = xa.x; x1 = xa.y; x2 = xa.z; x3 = xa.w;
        x4 = xb.x; x5 = xb.y; x6 = xb.z; x7 = xb.w;
    }

    float v0 = INFV, v1 = INFV, v2 = INFV, v3 = INFV;
    float v4 = INFV, v5 = INFV, v6 = INFV, v7 = INFV;
    float uprev = (tid == 0) ? 0.0f : INFV;   // DTW[-1][-1]=0 seed
    float yc = 0.0f, yd = 0.0f;               // y conveyor + 1-step delay
    float n3a = INFV, n3b = INFV;             // nv3 at t-1 / t-2 (chainH top)

    const float* ringR = ring + w * RROW + PAD;
    float*       ringW = ring + (w + 1) * RROW + PAD;

    for (int gb = 0; gb < GTOT; gb += CSTEP) {
        const int tau0 = gb - w * DSKEW;

        if (tau0 >= 0 && tau0 <= TAUMAX) {
            int yi = tau0 + lane;                    // clamp fake cols >= 2048
            if (yi >= NLEN) yi = NLEN - 1;
            const float yblk = yS[yi];               // 1 coalesced ds_read
            const float rblk = ringR[tau0 + lane];   // 1 coalesced ds_read
            float* wp = ringW + (tau0 - 2 * lane - 1);
            const bool isout = (tau0 == TAUMAX) & (w == NW - 1) & (lane == 63);

            #pragma unroll
            for (int s = 0; s < CSTEP; ++s) {
                const float yu  = rdlane(yblk, s);   // y[tau0+s] (scalar)
                const float ru  = rdlane(rblk, s);   // ring[tau0+s] (scalar)
                const float ycn = dpp_shr1(yd, yu);  // lane l: y[t-2l] (chainL)
                const float u   = dpp_shr1(v7, ru);  // above for row0 @ jL
                const float yH  = yc;                // lane l: y[t-2l-1] (chainH)
                // chainL: rows 0..3 @ col jL = t-2l
                float d0 = x0 - ycn; float nv0 = fmaf(d0, d0, min3f(v0, uprev, u));
                float d1 = x1 - ycn; float nv1 = fmaf(d1, d1, min3f(v1, v0, nv0));
                float d2 = x2 - ycn; float nv2 = fmaf(d2, d2, min3f(v2, v1, nv1));
                float d3 = x3 - ycn; float nv3 = fmaf(d3, d3, min3f(v3, v2, nv2));
                // chainH: rows 4..7 @ col jH = jL-1 (independent of chainL today)
                float d4 = x4 - yH;  float nv4 = fmaf(d4, d4, min3f(v4, n3b, n3a));
                float d5 = x5 - yH;  float nv5 = fmaf(d5, d5, min3f(v5, v4, nv4));
                float d6 = x6 - yH;  float nv6 = fmaf(d6, d6, min3f(v6, v5, nv5));
                float d7 = x7 - yH;  float nv7 = fmaf(d7, d7, min3f(v7, v6, nv6));
                wp[s] = nv7;                         // strip-bottom @ col jH
                uprev = u;
                yd = yc; yc = ycn;
                n3b = n3a; n3a = nv3;
                v0 = nv0; v1 = nv1; v2 = nv2; v3 = nv3;
                v4 = nv4; v5 = nv5; v6 = nv6; v7 = nv7;
                if (s == 62 && isout) out[0] = sqrtf(nv7);  // jH == 2047
            }
        }
        __syncthreads();
    }
}

extern "C" void kernel_launch(void* const* d_in, const int* in_sizes, int n_in,
                              void* d_out, int out_size, void* d_ws, size_t ws_size,
                              hipStream_t stream) {
    const float* x = (const float*)d_in[0];
    const float* y = (const float*)d_in[1];
    (void)in_sizes; (void)n_in; (void)out_size; (void)d_ws; (void)ws_size;
    dtw_kernel<<<1, 256, 0, stream>>>(x, y, (float*)d_out);
}

// Round 2
// 198.234 us; speedup vs baseline: 1.2187x; 1.2187x over previous
//
#include <hip/hip_runtime.h>
#include <math.h>

// DTW 2048x2048, squared-diff cost, out = sqrt(DTW[2047][2047]).
//
// Skew-1 wave pipeline, NW=4 waves (256 thr) on one CU, R=8 rows/lane.
// Lane l of wave w owns rows 8*(64w+l)..+7; at wave-step t it computes
// column j = t - l for its 8 rows (serial min3+fma chain).
//
// Zero per-step LDS reads: per 64-step block each wave does TWO coalesced
// ds_read_b32 (y[tau0+lane], ring[tau0+lane]); per step, v_readlane(blk, s)
// (compile-time s) yields the wave-uniform y[tau0+s] / ring[tau0+s], which
// are injected into two DPP wave_shr:1 conveyors:
//   yconv: lane l holds y[t-l] (its column's y)
//   u    : lane l holds lane l-1's row-7 value (above/diag input); lane 0
//          gets the ring injection (row above the strip).
//
// min3 via UNSIGNED-INT bitcast min: every DP value here is non-negative
// (sums of squares, INFV=1e30 sentinel, 0 seed), so IEEE float ordering ==
// unsigned ordering of the bit patterns. Integer umin(umin(a,b),c) fuses
// to v_min3_u32 unconditionally (fp fminf(fminf()) does NOT fuse without
// nnan), halving the loop-carried dependency chain: per cell the carried
// path is v_min3_u32 -> v_fma (bitcasts are register no-ops).
// (Round-1 lesson: inline-asm v_min3_f32 + restructure regressed 150->192us;
// this keeps the proven structure and lets the scheduler stay free.)
//
// Guard-free: INFV=1e30 absorbs adds (1e30 + d^2 == 1e30 in fp32), so
// inactive-lane "commits" are idempotent; OOB ring writes (j<0 on ramp-in,
// j>=2048 on ramp-out) land in pad regions. Every block tau0 in [0,2048]
// runs the identical unrolled body -- no ramp/steady split, no per-step
// guards. Output is stored at the unique step (tau0==2048, s==62, w=3,
// lane 63) where j==2047.
//
// Ring: unwrapped rows, PAD=64 left pad, cols -64..2111 valid. All lanes
// write their row-7 value each step; lane 63 (true strip boundary) writes
// each column last within the wave, and DSKEW=128 + barrier every 64 steps
// guarantees the producer completed wave-step tau0+127 >= j+63 for every
// column j <= tau0+63 the consumer's block-top read touches.

#define NLEN  2048
#define NW    4
#define CSTEP 64
#define DSKEW 128
#define PAD   64
#define RROW  (PAD + 2112)              // writes/reads span cols -64..2111
#define GTOT  2496                      // last block: w=3, tau0=2048
#define INFV  1e30f

__device__ __forceinline__ float dpp_shr1(float v, float inj) {
    int r = __builtin_amdgcn_update_dpp(
        __builtin_bit_cast(int, inj), __builtin_bit_cast(int, v),
        0x138 /*wave_shr:1*/, 0xF, 0xF, false /*lane0 keeps old=inj*/);
    return __builtin_bit_cast(float, r);
}
__device__ __forceinline__ float rdlane(float v, int l) {
    return __builtin_bit_cast(float,
        __builtin_amdgcn_readlane(__builtin_bit_cast(int, v), l));
}
// 3-input min on non-negative floats via unsigned bit-pattern compare.
// umin+umin fuses to a single v_min3_u32 (integer min3 fusion is
// unconditional in the AMDGPU backend; fp needs nnan we don't have).
__device__ __forceinline__ float min3f(float a, float b, float c) {
    unsigned ia = __builtin_bit_cast(unsigned, a);
    unsigned ib = __builtin_bit_cast(unsigned, b);
    unsigned ic = __builtin_bit_cast(unsigned, c);
    unsigned m  = __builtin_elementwise_min(
                      __builtin_elementwise_min(ia, ib), ic);
    return __builtin_bit_cast(float, m);
}

__global__ __launch_bounds__(256, 1) void dtw_kernel(const float* __restrict__ X,
                                                     const float* __restrict__ Y,
                                                     float* __restrict__ out) {
    __shared__ __align__(16) float yS[NLEN];
    __shared__ float ring[(NW + 1) * RROW];

    const int tid  = threadIdx.x;
    const int w    = tid >> 6;
    const int lane = tid & 63;

    {
        const float4* Y4 = (const float4*)Y;
        float4* y4 = (float4*)yS;
        y4[tid]       = Y4[tid];
        y4[tid + 256] = Y4[tid + 256];
    }
    // Entire ring INFV: virtual row -1, pads, and unwritten tails.
    for (int k = tid; k < (NW + 1) * RROW; k += 256) ring[k] = INFV;
    __syncthreads();

    float x0, x1, x2, x3, x4, x5, x6, x7;
    {
        const float4 xa = *(const float4*)&X[tid * 8];
        const float4 xb = *(const float4*)&X[tid * 8 + 4];
        x0 = xa.x; x1 = xa.y; x2 = xa.z; x3 = xa.w;
        x4 = xb.x; x5 = xb.y; x6 = xb.z; x7 = xb.w;
    }

    float v0 = INFV, v1 = INFV, v2 = INFV, v3 = INFV;
    float v4 = INFV, v5 = INFV, v6 = INFV, v7 = INFV;
    float uprev = (tid == 0) ? 0.0f : INFV;   // DTW[-1][-1]=0 seed
    float yconv = 0.0f;                       // y DPP conveyor

    const float* ringR = ring + w * RROW + PAD;
    float*       ringW = ring + (w + 1) * RROW + PAD;

    for (int gb = 0; gb < GTOT; gb += CSTEP) {
        const int tau0 = gb - w * DSKEW;

        if (tau0 >= 0 && tau0 <= NLEN) {
            int yi = tau0 + lane;                    // clamp for tau0==2048
            if (yi >= NLEN) yi = NLEN - 1;
            const float yblk = yS[yi];               // 1 coalesced ds_read
            const float rblk = ringR[tau0 + lane];   // 1 coalesced ds_read
            float* wp = ringW + (tau0 - lane);
            const bool isout = (tau0 == NLEN) & (w == NW - 1) & (lane == 63);

            #pragma unroll
            for (int s = 0; s < CSTEP; ++s) {
                const float yu = rdlane(yblk, s);    // y[tau0+s] (scalar)
                const float ru = rdlane(rblk, s);    // ring[tau0+s] (scalar)
                yconv = dpp_shr1(yconv, yu);         // lane l: y[tau0+s-l]
                const float u = dpp_shr1(v7, ru);    // above value
                float d0 = x0 - yconv; float nv0 = fmaf(d0, d0, min3f(v0, uprev, u));
                float d1 = x1 - yconv; float nv1 = fmaf(d1, d1, min3f(v1, v0, nv0));
                float d2 = x2 - yconv; float nv2 = fmaf(d2, d2, min3f(v2, v1, nv1));
                float d3 = x3 - yconv; float nv3 = fmaf(d3, d3, min3f(v3, v2, nv2));
                float d4 = x4 - yconv; float nv4 = fmaf(d4, d4, min3f(v4, v3, nv3));
                float d5 = x5 - yconv; float nv5 = fmaf(d5, d5, min3f(v5, v4, nv4));
                float d6 = x6 - yconv; float nv6 = fmaf(d6, d6, min3f(v6, v5, nv5));
                float d7 = x7 - yconv; float nv7 = fmaf(d7, d7, min3f(v7, v6, nv6));
                wp[s] = nv7;
                uprev = u;
                v0 = nv0; v1 = nv1; v2 = nv2; v3 = nv3;
                v4 = nv4; v5 = nv5; v6 = nv6; v7 = nv7;
                if (s == 62 && isout) out[0] = sqrtf(nv7);  // j == 2047
            }
        }
        __syncthreads();
    }
}

extern "C" void kernel_launch(void* const* d_in, const int* in_sizes, int n_in,
                              void* d_out, int out_size, void* d_ws, size_t ws_size,
                              hipStream_t stream) {
    const float* x = (const float*)d_in[0];
    const float* y = (const float*)d_in[1];
    (void)in_sizes; (void)n_in; (void)out_size; (void)d_ws; (void)ws_size;
    dtw_kernel<<<1, 256, 0, stream>>>(x, y, (float*)d_out);
}